// Round 10
// baseline (338.224 us; speedup 1.0000x reference)
//
#include <hip/hip_runtime.h>
#include <hip/hip_bf16.h>

#define NM 50000
#define HD 128
#define KNEI 8
#define BM 64
#define SPAD 136
#define NBLK ((NM + BM - 1) / BM)   // 782
#define NH ((size_t)NM * (size_t)HD)

typedef float  fx4   __attribute__((ext_vector_type(4)));
typedef short  s16x8 __attribute__((ext_vector_type(8)));
typedef short  s16x4 __attribute__((ext_vector_type(4)));

__device__ __forceinline__ float sigm_f(float x) {
    return __builtin_amdgcn_rcpf(1.0f + __expf(-x));
}
__device__ __forceinline__ float tanh_f(float x) {
    return 2.0f * sigm_f(2.0f * x) - 1.0f;
}
__device__ __forceinline__ unsigned short f2b(float f) {
    __hip_bfloat16 h = __float2bfloat16(f);
    return __builtin_bit_cast(unsigned short, h);
}
__device__ __forceinline__ float b2f(unsigned short u) {
    __hip_bfloat16 h = __builtin_bit_cast(__hip_bfloat16, u);
    return __bfloat162float(h);
}

#define MFMA16(a, b, c) __builtin_amdgcn_mfma_f32_16x16x32_bf16(a, b, c, 0, 0, 0)

// ---- staging helpers (caller syncs) ----

__device__ __forceinline__ void stage_W16(const unsigned short* __restrict__ W16,
                                          int ldw, int woff,
                                          unsigned short (*Ws)[SPAD], int tid)
{
    const int g  = tid >> 1;
    const int c0 = (tid & 1) << 6;
    const unsigned short* src = W16 + (size_t)g * ldw + woff + c0;
    #pragma unroll
    for (int j = 0; j < 64; j += 8)
        *(s16x8*)&Ws[g][c0 + j] = *(const s16x8*)(src + j);
}

__device__ __forceinline__ void stage_A32(const float* __restrict__ A, int row0,
                                          unsigned short (*As)[SPAD], int tid)
{
    const int r  = tid & 63;
    const int c0 = (tid >> 6) << 5;
    int gr = row0 + r; if (gr >= NM) gr = NM - 1;
    const float* ap = A + (size_t)gr * HD + c0;
    #pragma unroll
    for (int j = 0; j < 32; j += 8) {
        s16x8 s;
        #pragma unroll
        for (int q = 0; q < 8; ++q) s[q] = (short)f2b(ap[j + q]);
        *(s16x8*)&As[r][c0 + j] = s;
    }
}

__device__ __forceinline__ void stage_A16(const unsigned short* __restrict__ A16, int row0,
                                          unsigned short (*As)[SPAD], int tid)
{
    const int r  = tid & 63;
    const int c0 = (tid >> 6) << 5;
    int gr = row0 + r; if (gr >= NM) gr = NM - 1;
    const unsigned short* ap = A16 + (size_t)gr * HD + c0;
    #pragma unroll
    for (int j = 0; j < 32; j += 8)
        *(s16x8*)&As[r][c0 + j] = *(const s16x8*)(ap + j);
}

__device__ __forceinline__ void lds_to_g16(const unsigned short (*L)[SPAD], int row0,
                                           unsigned short* __restrict__ G, int tid)
{
    const int r  = tid & 63;
    const int c0 = (tid >> 6) << 5;
    const int gr = row0 + r;
    if (gr >= NM) return;
    #pragma unroll
    for (int j = 0; j < 32; j += 8)
        *(s16x8*)&G[(size_t)gr * HD + c0 + j] = *(const s16x8*)&L[r][c0 + j];
}

__device__ __forceinline__ void mfma_128(const unsigned short (*As)[SPAD],
                                         const unsigned short (*Ws)[SPAD],
                                         int w, int l, fx4 (&acc)[8])
{
    const int rb = w * 16 + (l & 15);
    const int kq = (l >> 4) << 3;
    #pragma unroll
    for (int ks = 0; ks < 4; ++ks) {
        const s16x8 a = *(const s16x8*)&As[rb][ks * 32 + kq];
        #pragma unroll
        for (int nf = 0; nf < 8; ++nf) {
            const s16x8 b = *(const s16x8*)&Ws[nf * 16 + (l & 15)][ks * 32 + kq];
            acc[nf] = MFMA16(a, b, acc[nf]);
        }
    }
}

#define ZACC(acc) { _Pragma("unroll") for (int z_ = 0; z_ < 8; ++z_) \
                    acc[z_] = (fx4)0.0f; }

// ---------- weight fp32 -> bf16 conversion ----------
__global__ __launch_bounds__(256)
void dgru_wcvt(const float* __restrict__ Wz, const float* __restrict__ Wr,
               const float* __restrict__ Ur, const float* __restrict__ Wh,
               unsigned short* __restrict__ w16)
{
    const int i = blockIdx.x * 256 + threadIdx.x;
    float v;
    if      (i < 32768) v = Wz[i];
    else if (i < 49152) v = Wr[i - 32768];
    else if (i < 65536) v = Ur[i - 49152];
    else                v = Wh[i - 65536];
    w16[i] = f2b(v);
}

// ---------- pre: fmess16 + pre_r16 + h0 + Uh0 (all bf16, no fp32 pre-acts) ----------
__global__ __launch_bounds__(256)
void dgru_pre(const float* __restrict__ fmess,
              const unsigned short* __restrict__ wz16,
              const unsigned short* __restrict__ wr16,
              const unsigned short* __restrict__ wh16,
              const unsigned short* __restrict__ ur16,
              const float* __restrict__ bz, const float* __restrict__ bh,
              const float* __restrict__ bur,
              unsigned short* __restrict__ fmess16,
              unsigned short* __restrict__ pre_r16,
              unsigned short* __restrict__ h16, unsigned short* __restrict__ uh16)
{
    __shared__ unsigned short As[BM][SPAD];
    __shared__ unsigned short Ws[HD][SPAD];
    const int tid  = threadIdx.x;
    const int row0 = blockIdx.x * BM;
    const int w    = tid >> 6;
    const int l    = tid & 63;

    stage_A32(fmess, row0, As, tid);
    stage_W16(wz16, 2 * HD, 0, Ws, tid);   // Wz1
    __syncthreads();

    lds_to_g16(As, row0, fmess16, tid);    // persist bf16 fmess for zh recompute

    fx4 accz[8]; ZACC(accz);
    mfma_128(As, Ws, w, l, accz);
    __syncthreads();                       // Ws readers done

    stage_W16(wr16, HD, 0, Ws, tid);
    __syncthreads();
    {
        fx4 accr[8]; ZACC(accr);
        mfma_128(As, Ws, w, l, accr);
        __syncthreads();                   // Ws readers done
        #pragma unroll
        for (int nf = 0; nf < 8; ++nf) {
            const int col = nf * 16 + (l & 15);
            #pragma unroll
            for (int q = 0; q < 4; ++q) {
                const int rl = w * 16 + ((l >> 4) << 2) + q;
                Ws[rl][col] = f2b(accr[nf][q]);
            }
        }
        __syncthreads();
        lds_to_g16(Ws, row0, pre_r16, tid);
        __syncthreads();                   // pre_r copies done before Wh restage
    }

    stage_W16(wh16, 2 * HD, 0, Ws, tid);   // Wh1
    __syncthreads();
    {
        fx4 acch[8]; ZACC(acch);
        mfma_128(As, Ws, w, l, acch);
        __syncthreads();                   // As & Ws readers done
        #pragma unroll
        for (int nf = 0; nf < 8; ++nf) {
            const int col = nf * 16 + (l & 15);
            const float bvz = bz[col];
            const float bvh = bh[col];
            #pragma unroll
            for (int q = 0; q < 4; ++q) {
                const int rl = w * 16 + ((l >> 4) << 2) + q;
                const int gr = row0 + rl;
                float h0 = sigm_f(accz[nf][q] + bvz) * tanh_f(acch[nf][q] + bvh);
                if (gr == 0) h0 = 0.0f;
                As[rl][col] = f2b(h0);
            }
        }
    }
    stage_W16(ur16, HD, 0, Ws, tid);
    __syncthreads();                       // h0 writes visible; Ws staged

    lds_to_g16(As, row0, h16, tid);
    {
        fx4 accu[8]; ZACC(accu);
        mfma_128(As, Ws, w, l, accu);
        __syncthreads();                   // Ws readers done
        #pragma unroll
        for (int nf = 0; nf < 8; ++nf) {
            const int col = nf * 16 + (l & 15);
            const float bv = bur[col];
            #pragma unroll
            for (int q = 0; q < 4; ++q) {
                const int rl = w * 16 + ((l >> 4) << 2) + q;
                Ws[rl][col] = f2b(accu[nf][q] + bv);
            }
        }
        __syncthreads();
        lds_to_g16(Ws, row0, uh16, tid);
    }
}

// ---------- gather (standalone, high occupancy): bf16 in, bf16 sums out ----------
__global__ __launch_bounds__(256)
void dgru_gather(const unsigned short* __restrict__ h16,
                 const unsigned short* __restrict__ uh16,
                 const int* __restrict__ bgraph,
                 const unsigned short* __restrict__ pre_r16,
                 unsigned short* __restrict__ sh16, unsigned short* __restrict__ sg16)
{
    const int tid = threadIdx.x;
    const int n   = blockIdx.x * 8 + (tid >> 5);   // grid covers NM exactly
    const int d0  = (tid & 31) << 2;

    const int4* bg = (const int4*)(bgraph + (size_t)n * KNEI);
    const int4 b0 = bg[0], b1 = bg[1];
    const int idx[KNEI] = {b0.x, b0.y, b0.z, b0.w, b1.x, b1.y, b1.z, b1.w};

    s16x4 hr[KNEI], ur[KNEI];
    #pragma unroll
    for (int k = 0; k < KNEI; ++k)
        hr[k] = *(const s16x4*)&h16[(size_t)idx[k] * HD + d0];
    #pragma unroll
    for (int k = 0; k < KNEI; ++k)
        ur[k] = *(const s16x4*)&uh16[(size_t)idx[k] * HD + d0];
    const s16x4 prb = *(const s16x4*)&pre_r16[(size_t)n * HD + d0];
    float pr[4];
    #pragma unroll
    for (int j = 0; j < 4; ++j) pr[j] = b2f((unsigned short)prb[j]);

    float sh[4] = {0.f, 0.f, 0.f, 0.f};
    float sg[4] = {0.f, 0.f, 0.f, 0.f};
    #pragma unroll
    for (int k = 0; k < KNEI; ++k) {
        #pragma unroll
        for (int j = 0; j < 4; ++j) {
            const float hv = b2f((unsigned short)hr[k][j]);
            const float uv = b2f((unsigned short)ur[k][j]);
            sh[j] += hv;
            sg[j] = fmaf(sigm_f(pr[j] + uv), hv, sg[j]);
        }
    }
    s16x4 osh, osg;
    #pragma unroll
    for (int j = 0; j < 4; ++j) {
        osh[j] = (short)f2b(sh[j]);
        osg[j] = (short)f2b(sg[j]);
    }
    const size_t o = (size_t)n * HD + d0;
    *(s16x4*)&sh16[o] = osh;
    *(s16x4*)&sg16[o] = osg;
}

// ---------- zh: recompute pre-acts from fmess16; z + GRU-update + next Uh ----------
__global__ __launch_bounds__(256)
void dgru_zh(const unsigned short* __restrict__ fmess16,
             const unsigned short* __restrict__ sh16,
             const unsigned short* __restrict__ sg16,
             const unsigned short* __restrict__ wz16,
             const unsigned short* __restrict__ wh16,
             const unsigned short* __restrict__ ur16,
             const float* __restrict__ bz, const float* __restrict__ bh,
             const float* __restrict__ bur,
             unsigned short* __restrict__ h16, unsigned short* __restrict__ uh16,
             float* __restrict__ hout, int last)
{
    __shared__ unsigned short AsF[BM][SPAD];   // fmess16 tile, later new h
    __shared__ unsigned short AsX[BM][SPAD];   // sum_h, then sum_g, then new Uh
    __shared__ unsigned short Ws[HD][SPAD];
    const int tid  = threadIdx.x;
    const int row0 = blockIdx.x * BM;
    const int w    = tid >> 6;
    const int l    = tid & 63;

    // ---- z = sigmoid(fmess@Wz1 + sum_h@Wz2 + bz) ----
    stage_A16(fmess16, row0, AsF, tid);
    stage_A16(sh16, row0, AsX, tid);
    stage_W16(wz16, 2 * HD, 0, Ws, tid);       // Wz1
    __syncthreads();                           // S1
    fx4 acc[8]; ZACC(acc);
    mfma_128(AsF, Ws, w, l, acc);
    __syncthreads();                           // S2: Ws readers done
    stage_W16(wz16, 2 * HD, HD, Ws, tid);      // Wz2
    __syncthreads();                           // S3
    mfma_128(AsX, Ws, w, l, acc);

    fx4 zres[8];
    float shv[8][4];
    #pragma unroll
    for (int nf = 0; nf < 8; ++nf) {
        const int col = nf * 16 + (l & 15);
        const float bv = bz[col];
        #pragma unroll
        for (int q = 0; q < 4; ++q) {
            const int rl = w * 16 + ((l >> 4) << 2) + q;
            zres[nf][q] = sigm_f(acc[nf][q] + bv);
            shv[nf][q]  = b2f(AsX[rl][col]);   // save sum_h before AsX reuse
        }
    }
    __syncthreads();                           // S4: AsX & Ws readers done

    // ---- pre_h = fmess@Wh1 + sum_g@Wh2 + bh ; h = (1-z)*sum_h + z*tanh(pre_h) ----
    stage_A16(sg16, row0, AsX, tid);
    stage_W16(wh16, 2 * HD, 0, Ws, tid);       // Wh1
    __syncthreads();                           // S5
    ZACC(acc);
    mfma_128(AsF, Ws, w, l, acc);
    __syncthreads();                           // S6: AsF & Ws readers done
    stage_W16(wh16, 2 * HD, HD, Ws, tid);      // Wh2
    __syncthreads();                           // S7
    mfma_128(AsX, Ws, w, l, acc);

    #pragma unroll
    for (int nf = 0; nf < 8; ++nf) {
        const int col = nf * 16 + (l & 15);
        const float bv = bh[col];
        #pragma unroll
        for (int q = 0; q < 4; ++q) {
            const int rl = w * 16 + ((l >> 4) << 2) + q;
            const int gr = row0 + rl;
            const float zz = zres[nf][q];
            float o = (1.0f - zz) * shv[nf][q] + zz * tanh_f(acc[nf][q] + bv);
            if (gr == 0) o = 0.0f;
            if (last) {
                if (gr < NM) hout[(size_t)gr * HD + col] = o;
            } else {
                AsF[rl][col] = f2b(o);         // AsF readers finished at S6
            }
        }
    }
    if (last) return;
    __syncthreads();                           // S8: h writes visible; AsX/Ws readers done

    // ---- Uh = h @ Ur.T + bur ----
    stage_W16(ur16, HD, 0, Ws, tid);
    lds_to_g16(AsF, row0, h16, tid);
    __syncthreads();                           // S9
    ZACC(acc);
    mfma_128(AsF, Ws, w, l, acc);
    #pragma unroll
    for (int nf = 0; nf < 8; ++nf) {
        const int col = nf * 16 + (l & 15);
        const float bv = bur[col];
        #pragma unroll
        for (int q = 0; q < 4; ++q) {
            const int rl = w * 16 + ((l >> 4) << 2) + q;
            AsX[rl][col] = f2b(acc[nf][q] + bv);   // AsX readers done at S8
        }
    }
    __syncthreads();                           // S10
    lds_to_g16(AsX, row0, uh16, tid);
}

extern "C" void kernel_launch(void* const* d_in, const int* in_sizes, int n_in,
                              void* d_out, int out_size, void* d_ws, size_t ws_size,
                              hipStream_t stream) {
    const float* fmess  = (const float*)d_in[0];
    const int*   bgraph = (const int*)  d_in[1];
    const float* W_z    = (const float*)d_in[2];
    const float* b_z    = (const float*)d_in[3];
    const float* W_r    = (const float*)d_in[4];
    const float* U_r    = (const float*)d_in[5];
    const float* b_Ur   = (const float*)d_in[6];
    const float* W_h    = (const float*)d_in[7];
    const float* b_h    = (const float*)d_in[8];

    unsigned short* ws16 = (unsigned short*)d_ws;
    unsigned short* fmess16 = ws16;
    unsigned short* pre_r16 = ws16 + NH;
    unsigned short* h16     = ws16 + 2 * NH;
    unsigned short* uh16    = ws16 + 3 * NH;
    unsigned short* sh16    = ws16 + 4 * NH;
    unsigned short* sg16    = ws16 + 5 * NH;
    unsigned short* w16     = ws16 + 6 * NH;
    unsigned short* wz16 = w16;                // [128][256]
    unsigned short* wr16 = w16 + 32768;        // [128][128]
    unsigned short* ur16 = w16 + 49152;        // [128][128]
    unsigned short* wh16 = w16 + 65536;        // [128][256]
    float* hout = (float*)d_out;
    // ws usage ~= 77 MB

    dgru_wcvt<<<dim3(384), dim3(256), 0, stream>>>(W_z, W_r, U_r, W_h, w16);

    dgru_pre<<<dim3(NBLK), dim3(256), 0, stream>>>(
        fmess, wz16, wr16, wh16, ur16, b_z, b_h, b_Ur,
        fmess16, pre_r16, h16, uh16);

    for (int it = 1; it < 5; ++it) {
        dgru_gather<<<dim3(NM / 8), dim3(256), 0, stream>>>(
            h16, uh16, bgraph, pre_r16, sh16, sg16);
        dgru_zh<<<dim3(NBLK), dim3(256), 0, stream>>>(
            fmess16, sh16, sg16, wz16, wh16, ur16, b_z, b_h, b_Ur,
            h16, uh16, hout, (it == 4) ? 1 : 0);
    }
}